// Round 3
// baseline (1119.984 us; speedup 1.0000x reference)
//
#include <hip/hip_runtime.h>
#include <cmath>

#define TOKENS 16384
#define DM     4096
#define NEXP   64
#define TPW    16   // tokens per wave

// ---------------- Kernel 0: wg[e][k] -> wgT4[kb][e] (float4 of k) -----------
// So that lane=e reads of the k-stream are fully coalesced (1 KB/wave/load).
__global__ __launch_bounds__(256)
void relayout_kernel(const float* __restrict__ wg, float4* __restrict__ wgT4)
{
    const int tid = blockIdx.x * 256 + threadIdx.x;  // 0..65535
    const int e   = tid >> 10;        // expert
    const int kb  = tid & 1023;       // k/4 block
    // coalesced read (consecutive kb, same row), scattered write (1 MB total)
    wgT4[(size_t)kb * NEXP + e] = ((const float4*)wg)[(size_t)e * (DM / 4) + kb];
}

// ---------------- Kernel 1: fused logits + softmax + top2 + partials --------
// 256 blocks x 512 threads (8 waves). lane = expert. Waves 0-3: k-half 0,
// waves 4-7: k-half 1, same 16-token groups; halves merged through LDS.
// x is read via wave-uniform scalar loads (s_load) -> scalar pipe.
__global__ __launch_bounds__(512)
void fused_kernel(const float* __restrict__ x, const float4* __restrict__ wgT4,
                  float* __restrict__ out, float* __restrict__ p_imp,
                  float* __restrict__ p_cnt)
{
    const int lane = threadIdx.x & 63;   // expert
    const int wave = threadIdx.x >> 6;   // 0..7
    const int wgrp = wave & 3;           // token group within block
    const int half = wave >> 2;          // k half

    // wave-uniform scalars (force SGPR so x loads hit the SMEM pipe)
    const int t0 = __builtin_amdgcn_readfirstlane((int)blockIdx.x * 64 + wgrp * TPW);
    const int k0 = __builtin_amdgcn_readfirstlane(half * (DM / 2));

    float acc[TPW];
    #pragma unroll
    for (int t = 0; t < TPW; ++t) acc[t] = 0.f;

    const float*  __restrict__ xbase = x + (size_t)t0 * DM + k0;
    const float4* __restrict__ wptr  = wgT4 + (size_t)(k0 >> 2) * NEXP + lane;

    #pragma unroll 2
    for (int kb = 0; kb < DM / 8; ++kb) {      // 512 iters x 4 k
        const float4 wv = wptr[(size_t)kb * NEXP];   // coalesced, streams from L2
        const float* __restrict__ xk = xbase + (kb << 2);
        #pragma unroll
        for (int t = 0; t < TPW; ++t) {
            const float* __restrict__ xr = xk + (size_t)t * DM;  // uniform -> s_load
            float a = acc[t];
            a = fmaf(xr[0], wv.x, a);
            a = fmaf(xr[1], wv.y, a);
            a = fmaf(xr[2], wv.z, a);
            a = fmaf(xr[3], wv.w, a);
            acc[t] = a;
        }
    }

    // merge k-halves: waves 4-7 publish, waves 0-3 consume
    __shared__ float lmerge[64][NEXP];   // 16 KB, all lanes same row per store
    if (half == 1) {
        #pragma unroll
        for (int t = 0; t < TPW; ++t) lmerge[wgrp * TPW + t][lane] = acc[t];
    }
    __syncthreads();

    __shared__ float rimp[4][NEXP];
    __shared__ float rcnt[4][NEXP];

    if (half == 0) {
        float imp_acc = 0.f, cnt_acc = 0.f;
        #pragma unroll 1
        for (int t = 0; t < TPW; ++t) {
            const int tok = t0 + t;
            const float v = acc[t] + lmerge[wgrp * TPW + t][lane];

            // softmax over 64 lanes
            float m = v;
            #pragma unroll
            for (int off = 32; off; off >>= 1) m = fmaxf(m, __shfl_xor(m, off));
            const float p = expf(v - m);
            float s = p;
            #pragma unroll
            for (int off = 32; off; off >>= 1) s += __shfl_xor(s, off);
            const float prob = p / s;

            // top-1 (ties -> lower index, matching lax.top_k)
            float bv = prob; int bi = lane;
            #pragma unroll
            for (int off = 32; off; off >>= 1) {
                const float ov = __shfl_xor(bv, off);
                const int   oi = __shfl_xor(bi, off);
                if (ov > bv || (ov == bv && oi < bi)) { bv = ov; bi = oi; }
            }
            // top-2: mask winner, reduce again
            float cv = (lane == bi) ? -1.0f : prob; int ci = lane;
            #pragma unroll
            for (int off = 32; off; off >>= 1) {
                const float ov = __shfl_xor(cv, off);
                const int   oi = __shfl_xor(ci, off);
                if (ov > cv || (ov == cv && oi < ci)) { cv = ov; ci = oi; }
            }

            if (lane == 0) {
                out[2 * tok]                  = (float)bi;
                out[2 * tok + 1]              = (float)ci;
                out[2 * TOKENS + 2 * tok]     = bv;
                out[2 * TOKENS + 2 * tok + 1] = cv;
            }
            imp_acc += prob;
            cnt_acc += (lane == bi) ? 1.0f : 0.0f;
        }
        rimp[wgrp][lane] = imp_acc;
        rcnt[wgrp][lane] = cnt_acc;
    }
    __syncthreads();

    if (threadIdx.x < NEXP) {
        const int e = threadIdx.x;
        p_imp[blockIdx.x * NEXP + e] = rimp[0][e] + rimp[1][e] + rimp[2][e] + rimp[3][e];
        p_cnt[blockIdx.x * NEXP + e] = rcnt[0][e] + rcnt[1][e] + rcnt[2][e] + rcnt[3][e];
    }
}

// ---------------- Kernel 2: aux = E * sum_e importance_e * load_e -----------
__global__ __launch_bounds__(256)
void aux_kernel(const float* __restrict__ p_imp, const float* __restrict__ p_cnt,
                float* __restrict__ out)
{
    __shared__ float s_imp[256];
    __shared__ float s_cnt[256];
    const int tid = threadIdx.x;
    const int e = tid & 63;
    const int c = tid >> 6;           // 4 chunks of 64 blocks
    float si = 0.f, sc = 0.f;
    for (int b = c * 64; b < c * 64 + 64; ++b) {
        si += p_imp[b * NEXP + e];
        sc += p_cnt[b * NEXP + e];
    }
    s_imp[tid] = si; s_cnt[tid] = sc;
    __syncthreads();
    if (tid < 64) {
        const float imp = s_imp[tid] + s_imp[64 + tid] + s_imp[128 + tid] + s_imp[192 + tid];
        const float cnt = s_cnt[tid] + s_cnt[64 + tid] + s_cnt[128 + tid] + s_cnt[192 + tid];
        float prod = imp * cnt;
        #pragma unroll
        for (int off = 32; off; off >>= 1) prod += __shfl_xor(prod, off);
        if (tid == 0) {
            out[4 * TOKENS] = (float)NEXP * prod / ((float)TOKENS * (float)TOKENS);
        }
    }
}

extern "C" void kernel_launch(void* const* d_in, const int* in_sizes, int n_in,
                              void* d_out, int out_size, void* d_ws, size_t ws_size,
                              hipStream_t stream) {
    const float* x  = (const float*)d_in[0];
    const float* wg = (const float*)d_in[1];
    float* out = (float*)d_out;

    float4* wgT4  = (float4*)d_ws;                       // 1 MB
    float*  p_imp = (float*)d_ws + 4 * 65536;            // 256*64 floats
    float*  p_cnt = p_imp + 256 * NEXP;

    relayout_kernel<<<256, 256, 0, stream>>>(wg, wgT4);
    fused_kernel<<<TOKENS / 64, 512, 0, stream>>>(x, wgT4, out, p_imp, p_cnt);
    aux_kernel<<<1, 256, 0, stream>>>(p_imp, p_cnt, out);
}

// Round 4
// 404.009 us; speedup vs baseline: 2.7722x; 2.7722x over previous
//
#include <hip/hip_runtime.h>
#include <cmath>

#define TOKENS 16384
#define DM     4096
#define NEXP   64
#define S_W    64.0f     // wg pre-scale (keeps wh out of half-denormal range)
#define S_LO   2048.0f   // lo-channel scale (keeps xl/wl normal halves)

typedef _Float16 half8 __attribute__((ext_vector_type(8)));
typedef float    f32x4 __attribute__((ext_vector_type(4)));

// ws layout: whB[262144] halves | wlB[262144] halves | gsum[128] f32 (imp|cnt)

// ---------- Kernel P: wg -> B-fragment-ordered fp16 hi/lo + zero gsum -------
// block = (kb, et); lane holds B[k=8*(lane>>4)+j][n=(lane&15)] for j=0..7.
__global__ __launch_bounds__(64)
void prep_kernel(const float* __restrict__ wg, _Float16* __restrict__ whB,
                 _Float16* __restrict__ wlB, float* __restrict__ gsum)
{
    const int kb = blockIdx.x >> 2;
    const int et = blockIdx.x & 3;
    const int l  = threadIdx.x;
    const int e  = et * 16 + (l & 15);
    const int k0 = kb * 32 + 8 * (l >> 4);

    const float* wp = wg + (size_t)e * DM + k0;
    float v[8];
    *(float4*)(v)     = *(const float4*)(wp);
    *(float4*)(v + 4) = *(const float4*)(wp + 4);

    half8 hh, ll;
    #pragma unroll
    for (int j = 0; j < 8; ++j) {
        const float ws = v[j] * S_W;
        const _Float16 h = (_Float16)ws;
        hh[j] = h;
        ll[j] = (_Float16)((ws - (float)h) * S_LO);
    }
    const int idx = blockIdx.x * 64 + l;   // (kb*4+et)*64 + lane
    ((half8*)whB)[idx] = hh;
    ((half8*)wlB)[idx] = ll;

    if (blockIdx.x == 0) { gsum[l] = 0.f; gsum[64 + l] = 0.f; }
}

// ---------- Kernel M: fp16-split MFMA logits + fused gate -------------------
// 512 blocks x 256 thr (4 waves): wave = (tgrp in [0,2)) + 2*(khalf in [0,2)).
// Each wave: 16 tokens x 64 experts over half of K. LDS merge of k-halves,
// then khalf==0 waves do softmax/top-2/partials.
__global__ __launch_bounds__(256)
void moe_kernel(const float* __restrict__ x, const _Float16* __restrict__ whB,
                const _Float16* __restrict__ wlB, float* __restrict__ out,
                float* __restrict__ gsum)
{
    const int lane  = threadIdx.x & 63;
    const int wave  = threadIdx.x >> 6;
    const int tgrp  = wave & 1;
    const int khalf = wave >> 1;
    const int sub   = lane & 15;
    const int q     = lane >> 4;
    const int t0    = blockIdx.x * 32 + tgrp * 16;

    f32x4 ahh[4] = {};
    f32x4 amd[4] = {};

    // A-frag natural global read: lane -> (token t0+sub, k = kb*32 + 8q + j)
    const float* xp = x + (size_t)(t0 + sub) * DM + 8 * q;
    const half8* whv = (const half8*)whB;
    const half8* wlv = (const half8*)wlB;

    const int kb0 = khalf * 64, kbe = kb0 + 64;
    float4 a0 = *(const float4*)(xp + kb0 * 32);
    float4 a1 = *(const float4*)(xp + kb0 * 32 + 4);

    for (int kb = kb0; kb < kbe; ++kb) {
        const int kn = (kb + 1 < kbe) ? kb + 1 : kb;   // uniform, in-bounds
        float4 n0 = *(const float4*)(xp + kn * 32);
        float4 n1 = *(const float4*)(xp + kn * 32 + 4);

        half8 bh[4], bl[4];
        const int bbase = kb * 256 + lane;
        #pragma unroll
        for (int et = 0; et < 4; ++et) {
            bh[et] = whv[bbase + et * 64];
            bl[et] = wlv[bbase + et * 64];
        }

        float v[8];
        *(float4*)(v)     = a0;
        *(float4*)(v + 4) = a1;
        half8 xh, xl;
        #pragma unroll
        for (int j = 0; j < 8; ++j) {
            const _Float16 h = (_Float16)v[j];
            xh[j] = h;
            xl[j] = (_Float16)((v[j] - (float)h) * S_LO);
        }

        #pragma unroll
        for (int et = 0; et < 4; ++et) {
            ahh[et] = __builtin_amdgcn_mfma_f32_16x16x32_f16(xh, bh[et], ahh[et], 0, 0, 0);
            amd[et] = __builtin_amdgcn_mfma_f32_16x16x32_f16(xh, bl[et], amd[et], 0, 0, 0);
            amd[et] = __builtin_amdgcn_mfma_f32_16x16x32_f16(xl, bh[et], amd[et], 0, 0, 0);
        }
        a0 = n0; a1 = n1;
    }

    // logits = (hh + mid/2048) / 64 ; C/D: expert = sub+16*et, token = 4q+reg
    float lg[4][4];
    #pragma unroll
    for (int et = 0; et < 4; ++et)
        #pragma unroll
        for (int r = 0; r < 4; ++r)
            lg[et][r] = (ahh[et][r] + amd[et][r] * (1.0f / S_LO)) * (1.0f / S_W);

    __shared__ float lmerge[2][16][64];
    __shared__ float bimp[2][64], bcnt[2][64];

    if (khalf == 1) {
        #pragma unroll
        for (int et = 0; et < 4; ++et)
            #pragma unroll
            for (int r = 0; r < 4; ++r)
                lmerge[tgrp][4 * q + r][sub + 16 * et] = lg[et][r];
    }
    __syncthreads();

    if (khalf == 0) {
        float imp[4] = {0, 0, 0, 0}, cnt[4] = {0, 0, 0, 0};
        #pragma unroll
        for (int et = 0; et < 4; ++et)
            #pragma unroll
            for (int r = 0; r < 4; ++r)
                lg[et][r] += lmerge[tgrp][4 * q + r][sub + 16 * et];

        for (int r = 0; r < 4; ++r) {
            const int tok = t0 + 4 * q + r;
            float m = fmaxf(fmaxf(lg[0][r], lg[1][r]), fmaxf(lg[2][r], lg[3][r]));
            #pragma unroll
            for (int off = 1; off < 16; off <<= 1) m = fmaxf(m, __shfl_xor(m, off));
            float p[4]; float s = 0.f;
            #pragma unroll
            for (int et = 0; et < 4; ++et) { p[et] = expf(lg[et][r] - m); s += p[et]; }
            #pragma unroll
            for (int off = 1; off < 16; off <<= 1) s += __shfl_xor(s, off);
            #pragma unroll
            for (int et = 0; et < 4; ++et) p[et] = p[et] / s;

            // local top-2 (ties -> lower index; ids increase with et)
            float v1, v2; int i1, i2;
            if (p[1] > p[0]) { v1 = p[1]; i1 = sub + 16; v2 = p[0]; i2 = sub; }
            else             { v1 = p[0]; i1 = sub;      v2 = p[1]; i2 = sub + 16; }
            #pragma unroll
            for (int et = 2; et < 4; ++et) {
                const float vv = p[et]; const int id = sub + 16 * et;
                if (vv > v1)      { v2 = v1; i2 = i1; v1 = vv; i1 = id; }
                else if (vv > v2) { v2 = vv; i2 = id; }
            }
            // cross-lane merge within the 16-lane token group
            #pragma unroll
            for (int off = 1; off < 16; off <<= 1) {
                const float w1 = __shfl_xor(v1, off), w2 = __shfl_xor(v2, off);
                const int   j1 = __shfl_xor(i1, off), j2 = __shfl_xor(i2, off);
                if (w1 > v1 || (w1 == v1 && j1 < i1)) {
                    if (v1 > w2 || (v1 == w2 && i1 < j2)) { v2 = v1; i2 = i1; }
                    else                                   { v2 = w2; i2 = j2; }
                    v1 = w1; i1 = j1;
                } else {
                    if (w1 > v2 || (w1 == v2 && j1 < i2)) { v2 = w1; i2 = j1; }
                }
            }

            if (sub == 0) {
                out[2 * tok]                  = (float)i1;
                out[2 * tok + 1]              = (float)i2;
                out[2 * TOKENS + 2 * tok]     = v1;
                out[2 * TOKENS + 2 * tok + 1] = v2;
            }
            #pragma unroll
            for (int et = 0; et < 4; ++et) {
                imp[et] += p[et];
                if (i1 == sub + 16 * et) cnt[et] += 1.0f;
            }
        }
        #pragma unroll
        for (int et = 0; et < 4; ++et) {
            imp[et] += __shfl_xor(imp[et], 16); imp[et] += __shfl_xor(imp[et], 32);
            cnt[et] += __shfl_xor(cnt[et], 16); cnt[et] += __shfl_xor(cnt[et], 32);
        }
        if (q == 0) {
            #pragma unroll
            for (int et = 0; et < 4; ++et) {
                bimp[tgrp][sub + 16 * et] = imp[et];
                bcnt[tgrp][sub + 16 * et] = cnt[et];
            }
        }
    }
    __syncthreads();

    if (wave == 0) {
        atomicAdd(gsum + lane,      bimp[0][lane] + bimp[1][lane]);
        atomicAdd(gsum + 64 + lane, bcnt[0][lane] + bcnt[1][lane]);
    }
}

// ---------- Kernel C: aux = E * sum_e (imp/S)*(cnt/S) -----------------------
__global__ __launch_bounds__(64)
void aux_kernel(const float* __restrict__ gsum, float* __restrict__ out)
{
    const int l = threadIdx.x;
    float prod = gsum[l] * gsum[64 + l];
    #pragma unroll
    for (int off = 32; off; off >>= 1) prod += __shfl_xor(prod, off);
    if (l == 0)
        out[4 * TOKENS] = (float)NEXP * prod / ((float)TOKENS * (float)TOKENS);
}

extern "C" void kernel_launch(void* const* d_in, const int* in_sizes, int n_in,
                              void* d_out, int out_size, void* d_ws, size_t ws_size,
                              hipStream_t stream) {
    const float* x  = (const float*)d_in[0];
    const float* wg = (const float*)d_in[1];
    float* out = (float*)d_out;

    _Float16* whB = (_Float16*)d_ws;            // 512 KB
    _Float16* wlB = whB + 262144;               // 512 KB
    float*    gsum = (float*)(wlB + 262144);    // 128 floats: imp | cnt

    prep_kernel<<<512, 64, 0, stream>>>(wg, whB, wlB, gsum);
    moe_kernel<<<512, 256, 0, stream>>>(x, whB, wlB, out, gsum);
    aux_kernel<<<1, 64, 0, stream>>>(gsum, out);
}